// Round 1
// baseline (282.447 us; speedup 1.0000x reference)
//
#include <hip/hip_runtime.h>

#define NCC_EPS 1.1920929e-07f

// ---------------------------------------------------------------------------
// Fused single-scale NCC: per block = one 16x16 (H,W) tile x one D-chunk.
// March along D keeping a WIN-deep register ring of HW-box-filtered slices
// (5 channels: I, J, I^2, J^2, I*J) and running D-window sums.
// Box filter = zero-padded sum / win^3 (matches reference conv semantics).
// ---------------------------------------------------------------------------
template<int WIN>
__global__ __launch_bounds__(256)
void ncc_scale_kernel(const float* __restrict__ I, const float* __restrict__ J,
                      int D, int H, int W,
                      int tilesH, int tilesW, int chunksD, int chunkLen,
                      double* __restrict__ acc)
{
    constexpr int RAD = WIN / 2;
    constexpr int TH = 16, TW = 16;
    constexpr int SH = TH + 2 * RAD;   // staged rows (with halo)
    constexpr int SW = TW + 2 * RAD;   // staged cols (with halo)
    constexpr float invV = 1.0f / (float)(WIN * WIN * WIN);

    __shared__ float sI[SH * SW];
    __shared__ float sJ[SH * SW];
    __shared__ float wb[5][SH * TW];   // W-filtered products, full H halo extent
    __shared__ float red[4];

    int bid = blockIdx.x;
    int tw = bid % tilesW; bid /= tilesW;
    int th = bid % tilesH; bid /= tilesH;
    int cd = bid % chunksD; bid /= chunksD;
    int b  = bid;

    const int h0 = th * TH, w0 = tw * TW;
    const int z0 = cd * chunkLen;
    const int z1 = min(z0 + chunkLen, D);

    const size_t plane = (size_t)H * W;
    const float* Ib = I + (size_t)b * D * plane;
    const float* Jb = J + (size_t)b * D * plane;

    const int t  = threadIdx.x;
    const int hh = t / TW, ww = t % TW;       // this thread's owned output point
    const int gh = h0 + hh, gw = w0 + ww;
    const bool valid = (gh < H) && (gw < W);

    // register ring buffer of HW-filtered slices (static indexing only)
    float ring[WIN][5];
    float rs[5];
    #pragma unroll
    for (int s = 0; s < WIN; ++s)
        #pragma unroll
        for (int c = 0; c < 5; ++c) ring[s][c] = 0.f;
    #pragma unroll
    for (int c = 0; c < 5; ++c) rs[c] = 0.f;

    float ccsum = 0.f;

    const int zend = z1 + RAD;     // last input slice needed (exclusive)
    for (int zb = z0 - RAD; zb < zend; zb += WIN) {
        #pragma unroll
        for (int ph = 0; ph < WIN; ++ph) {
            const int z = zb + ph;              // uniform across block
            if (z < zend) {
                const bool zin = (z >= 0) && (z < D);
                // ---- stage I/J halo patch for slice z (zero padding) ----
                for (int idx = t; idx < SH * SW; idx += 256) {
                    int r = idx / SW, c = idx % SW;
                    int gh2 = h0 + r - RAD, gw2 = w0 + c - RAD;
                    float vi = 0.f, vj = 0.f;
                    if (zin && gh2 >= 0 && gh2 < H && gw2 >= 0 && gw2 < W) {
                        size_t off = (size_t)z * plane + (size_t)gh2 * W + gw2;
                        vi = Ib[off];
                        vj = Jb[off];
                    }
                    sI[idx] = vi;
                    sJ[idx] = vj;
                }
                __syncthreads();
                // ---- filter along W: 5 product channels ----
                for (int idx = t; idx < SH * TW; idx += 256) {
                    int r = idx / TW, c = idx % TW;
                    float a0 = 0, a1 = 0, a2 = 0, a3 = 0, a4 = 0;
                    #pragma unroll
                    for (int dw = 0; dw < WIN; ++dw) {
                        float vi = sI[r * SW + c + dw];
                        float vj = sJ[r * SW + c + dw];
                        a0 += vi; a1 += vj;
                        a2 += vi * vi; a3 += vj * vj; a4 += vi * vj;
                    }
                    wb[0][idx] = a0; wb[1][idx] = a1; wb[2][idx] = a2;
                    wb[3][idx] = a3; wb[4][idx] = a4;
                }
                __syncthreads();
                // ---- filter along H at this thread's point + ring update ----
                float n0 = 0, n1 = 0, n2 = 0, n3 = 0, n4 = 0;
                #pragma unroll
                for (int dh = 0; dh < WIN; ++dh) {
                    int idx2 = (hh + dh) * TW + ww;
                    n0 += wb[0][idx2]; n1 += wb[1][idx2]; n2 += wb[2][idx2];
                    n3 += wb[3][idx2]; n4 += wb[4][idx2];
                }
                rs[0] += n0 - ring[ph][0]; ring[ph][0] = n0;
                rs[1] += n1 - ring[ph][1]; ring[ph][1] = n1;
                rs[2] += n2 - ring[ph][2]; ring[ph][2] = n2;
                rs[3] += n3 - ring[ph][3]; ring[ph][3] = n3;
                rs[4] += n4 - ring[ph][4]; ring[ph][4] = n4;

                // ---- emit cc for output slice zo = z - RAD ----
                const int zo = z - RAD;
                if (valid && zo >= z0) {
                    float muI = rs[0] * invV;
                    float muJ = rs[1] * invV;
                    float sII = rs[2] * invV - muI * muI;   // sigma_I^2
                    float sJJ = rs[3] * invV - muJ * muJ;   // sigma_J^2
                    float s12 = rs[4] * invV - muI * muJ;   // sigma_IJ
                    float cc = (s12 * s12) / fmaxf(sII * sJJ, NCC_EPS);
                    ccsum += cc;
                }
            }
        }
    }

    // ---- block reduction -> global double accumulator ----
    for (int off = 32; off > 0; off >>= 1)
        ccsum += __shfl_down(ccsum, off);
    const int wid = t >> 6, lane = t & 63;
    if (lane == 0) red[wid] = ccsum;
    __syncthreads();
    if (t == 0) {
        float s = red[0] + red[1] + red[2] + red[3];
        atomicAdd(acc, (double)s);
    }
}

// ---------------------------------------------------------------------------
// avg_pool3d, k=3, stride=2, pad=1, count_include_pad=False
// ---------------------------------------------------------------------------
__global__ void pool_kernel(const float* __restrict__ in, float* __restrict__ out,
                            int D, int H, int W, int oD, int oH, int oW, int total)
{
    int idx = blockIdx.x * 256 + threadIdx.x;
    if (idx >= total) return;
    int ow = idx % oW; int tmp = idx / oW;
    int oh = tmp % oH; tmp /= oH;
    int od = tmp % oD; int b = tmp / oD;

    int d0 = 2 * od - 1, h0 = 2 * oh - 1, w0 = 2 * ow - 1;
    int dlo = max(d0, 0), dhi = min(d0 + 3, D);
    int hlo = max(h0, 0), hhi = min(h0 + 3, H);
    int wlo = max(w0, 0), whi = min(w0 + 3, W);

    const float* ib = in + (size_t)b * D * H * W;
    float s = 0.f;
    for (int d = dlo; d < dhi; ++d)
        for (int h = hlo; h < hhi; ++h)
            for (int w = wlo; w < whi; ++w)
                s += ib[((size_t)d * H + h) * W + w];
    int cnt = (dhi - dlo) * (hhi - hlo) * (whi - wlo);
    out[idx] = s / (float)cnt;
}

__global__ void finalize_kernel(const double* __restrict__ acc, float* __restrict__ out)
{
    double m = acc[0] / 9830400.0 + acc[1] / 1228800.0 + acc[2] / 153600.0;
    out[0] = (float)(-m / 3.0);
}

extern "C" void kernel_launch(void* const* d_in, const int* in_sizes, int n_in,
                              void* d_out, int out_size, void* d_ws, size_t ws_size,
                              hipStream_t stream)
{
    const float* I0 = (const float*)d_in[0];
    const float* J0 = (const float*)d_in[1];
    float* out = (float*)d_out;

    char* ws = (char*)d_ws;
    double* acc = (double*)ws;                         // 3 doubles
    float* I1 = (float*)(ws + 256);
    float* J1 = I1 + (size_t)2 * 80 * 96 * 80;
    float* I2 = J1 + (size_t)2 * 80 * 96 * 80;
    float* J2 = I2 + (size_t)2 * 40 * 48 * 40;

    hipMemsetAsync(acc, 0, 3 * sizeof(double), stream);

    // ---- scale 0: 160x192x160, win=9 ----
    {
        int H = 192, W = 160, D = 160;
        int tilesH = (H + 15) / 16, tilesW = (W + 15) / 16;
        int chunksD = 4, chunkLen = (D + chunksD - 1) / chunksD;
        int blocks = 2 * tilesH * tilesW * chunksD;
        ncc_scale_kernel<9><<<blocks, 256, 0, stream>>>(I0, J0, D, H, W,
                                                        tilesH, tilesW, chunksD, chunkLen,
                                                        acc + 0);
    }
    // ---- pool level 0 -> 1 ----
    {
        int total = 2 * 80 * 96 * 80;
        int blocks = (total + 255) / 256;
        pool_kernel<<<blocks, 256, 0, stream>>>(I0, I1, 160, 192, 160, 80, 96, 80, total);
        pool_kernel<<<blocks, 256, 0, stream>>>(J0, J1, 160, 192, 160, 80, 96, 80, total);
    }
    // ---- scale 1: 80x96x80, win=7 ----
    {
        int H = 96, W = 80, D = 80;
        int tilesH = (H + 15) / 16, tilesW = (W + 15) / 16;
        int chunksD = 4, chunkLen = (D + chunksD - 1) / chunksD;
        int blocks = 2 * tilesH * tilesW * chunksD;
        ncc_scale_kernel<7><<<blocks, 256, 0, stream>>>(I1, J1, D, H, W,
                                                        tilesH, tilesW, chunksD, chunkLen,
                                                        acc + 1);
    }
    // ---- pool level 1 -> 2 ----
    {
        int total = 2 * 40 * 48 * 40;
        int blocks = (total + 255) / 256;
        pool_kernel<<<blocks, 256, 0, stream>>>(I1, I2, 80, 96, 80, 40, 48, 40, total);
        pool_kernel<<<blocks, 256, 0, stream>>>(J1, J2, 80, 96, 80, 40, 48, 40, total);
    }
    // ---- scale 2: 40x48x40, win=5 ----
    {
        int H = 48, W = 40, D = 40;
        int tilesH = (H + 15) / 16, tilesW = (W + 15) / 16;
        int chunksD = 2, chunkLen = (D + chunksD - 1) / chunksD;
        int blocks = 2 * tilesH * tilesW * chunksD;
        ncc_scale_kernel<5><<<blocks, 256, 0, stream>>>(I2, J2, D, H, W,
                                                        tilesH, tilesW, chunksD, chunkLen,
                                                        acc + 2);
    }

    finalize_kernel<<<1, 1, 0, stream>>>(acc, out);
}

// Round 2
// 242.634 us; speedup vs baseline: 1.1641x; 1.1641x over previous
//
#include <hip/hip_runtime.h>

#define NCC_EPS 1.1920929e-07f

// ---------------------------------------------------------------------------
// Fused single-scale NCC: per block = one 16x16 (H,W) tile x one D-chunk.
// March along D keeping a WIN-deep register ring of HW-box-filtered slices
// (5 channels: I, J, I^2, J^2, I*J) and running D-window sums.
// Box filter = zero-padded sum / win^3 (matches reference conv semantics).
// ---------------------------------------------------------------------------
template<int WIN>
__global__ __launch_bounds__(256)
void ncc_scale_kernel(const float* __restrict__ I, const float* __restrict__ J,
                      int D, int H, int W,
                      int tilesH, int tilesW, int chunksD, int chunkLen,
                      double* __restrict__ acc)
{
    constexpr int RAD = WIN / 2;
    constexpr int TH = 16, TW = 16;
    constexpr int SH = TH + 2 * RAD;   // staged rows (with halo)
    constexpr int SW = TW + 2 * RAD;   // staged cols (with halo)
    constexpr int SPTS = SH * SW;
    constexpr float invV = 1.0f / (float)(WIN * WIN * WIN);

    __shared__ float sI[SPTS];
    __shared__ float sJ[SPTS];
    __shared__ float wb[5][SH * TW];   // W-filtered products, full H halo extent
    __shared__ float red[4];

    int bid = blockIdx.x;
    int tw = bid % tilesW; bid /= tilesW;
    int th = bid % tilesH; bid /= tilesH;
    int cd = bid % chunksD; bid /= chunksD;
    int b  = bid;

    const int h0 = th * TH, w0 = tw * TW;
    const int z0 = cd * chunkLen;
    const int z1 = min(z0 + chunkLen, D);

    // block-uniform: is the whole staged H/W patch in-bounds?
    const bool intHW = (h0 >= RAD) && (h0 + TH + RAD <= H) &&
                       (w0 >= RAD) && (w0 + TW + RAD <= W);

    const size_t plane = (size_t)H * W;
    const float* Ib = I + (size_t)b * D * plane;
    const float* Jb = J + (size_t)b * D * plane;

    const int t  = threadIdx.x;
    const int hh = t / TW, ww = t % TW;       // this thread's owned output point
    const int gh = h0 + hh, gw = w0 + ww;
    const bool valid = (gh < H) && (gw < W);

    // register ring buffer of HW-filtered slices (static indexing only)
    float ring[WIN][5];
    float rs[5];
    #pragma unroll
    for (int s = 0; s < WIN; ++s)
        #pragma unroll
        for (int c = 0; c < 5; ++c) ring[s][c] = 0.f;
    #pragma unroll
    for (int c = 0; c < 5; ++c) rs[c] = 0.f;

    float ccsum = 0.f;

    const int zend = z1 + RAD;     // last input slice needed (exclusive)
    for (int zb = z0 - RAD; zb < zend; zb += WIN) {
        #pragma unroll
        for (int ph = 0; ph < WIN; ++ph) {
            const int z = zb + ph;              // uniform across block
            if (z < zend) {
                const bool zin = (z >= 0) && (z < D);   // uniform
                float n0 = 0, n1 = 0, n2 = 0, n3 = 0, n4 = 0;
                if (zin) {
                    // ---- stage I/J halo patch for slice z (zero padding) ----
                    if (intHW) {
                        const float* pI = Ib + (size_t)z * plane + (size_t)(h0 - RAD) * W + (w0 - RAD);
                        const float* pJ = Jb + (size_t)z * plane + (size_t)(h0 - RAD) * W + (w0 - RAD);
                        #pragma unroll
                        for (int k = 0; k < (SPTS + 255) / 256; ++k) {
                            int idx = t + k * 256;
                            if (idx < SPTS) {
                                int r = idx / SW, c = idx - r * SW;
                                int off = r * W + c;
                                sI[idx] = pI[off];
                                sJ[idx] = pJ[off];
                            }
                        }
                    } else {
                        #pragma unroll
                        for (int k = 0; k < (SPTS + 255) / 256; ++k) {
                            int idx = t + k * 256;
                            if (idx < SPTS) {
                                int r = idx / SW, c = idx - r * SW;
                                int gh2 = h0 + r - RAD, gw2 = w0 + c - RAD;
                                float vi = 0.f, vj = 0.f;
                                if (gh2 >= 0 && gh2 < H && gw2 >= 0 && gw2 < W) {
                                    size_t off = (size_t)z * plane + (size_t)gh2 * W + gw2;
                                    vi = Ib[off];
                                    vj = Jb[off];
                                }
                                sI[idx] = vi;
                                sJ[idx] = vj;
                            }
                        }
                    }
                    __syncthreads();
                    // ---- filter along W: 5 product channels ----
                    #pragma unroll
                    for (int k = 0; k < (SH * TW + 255) / 256; ++k) {
                        int idx = t + k * 256;
                        if (idx < SH * TW) {
                            int r = idx / TW, c = idx - r * TW;
                            float a0 = 0, a1 = 0, a2 = 0, a3 = 0, a4 = 0;
                            #pragma unroll
                            for (int dw = 0; dw < WIN; ++dw) {
                                float vi = sI[r * SW + c + dw];
                                float vj = sJ[r * SW + c + dw];
                                a0 += vi; a1 += vj;
                                a2 += vi * vi; a3 += vj * vj; a4 += vi * vj;
                            }
                            wb[0][idx] = a0; wb[1][idx] = a1; wb[2][idx] = a2;
                            wb[3][idx] = a3; wb[4][idx] = a4;
                        }
                    }
                    __syncthreads();
                    // ---- filter along H at this thread's point ----
                    #pragma unroll
                    for (int dh = 0; dh < WIN; ++dh) {
                        int idx2 = (hh + dh) * TW + ww;
                        n0 += wb[0][idx2]; n1 += wb[1][idx2]; n2 += wb[2][idx2];
                        n3 += wb[3][idx2]; n4 += wb[4][idx2];
                    }
                }
                // ---- ring update (n == 0 for out-of-range slices) ----
                rs[0] += n0 - ring[ph][0]; ring[ph][0] = n0;
                rs[1] += n1 - ring[ph][1]; ring[ph][1] = n1;
                rs[2] += n2 - ring[ph][2]; ring[ph][2] = n2;
                rs[3] += n3 - ring[ph][3]; ring[ph][3] = n3;
                rs[4] += n4 - ring[ph][4]; ring[ph][4] = n4;

                // ---- emit cc for output slice zo = z - RAD ----
                const int zo = z - RAD;
                if (valid && zo >= z0) {
                    float muI = rs[0] * invV;
                    float muJ = rs[1] * invV;
                    float sII = rs[2] * invV - muI * muI;   // sigma_I^2
                    float sJJ = rs[3] * invV - muJ * muJ;   // sigma_J^2
                    float s12 = rs[4] * invV - muI * muJ;   // sigma_IJ
                    float cc = (s12 * s12) / fmaxf(sII * sJJ, NCC_EPS);
                    ccsum += cc;
                }
            }
        }
    }

    // ---- block reduction -> global double accumulator ----
    for (int off = 32; off > 0; off >>= 1)
        ccsum += __shfl_down(ccsum, off);
    const int wid = t >> 6, lane = t & 63;
    if (lane == 0) red[wid] = ccsum;
    __syncthreads();
    if (t == 0) {
        float s = red[0] + red[1] + red[2] + red[3];
        atomicAdd(acc, (double)s);
    }
}

// ---------------------------------------------------------------------------
// avg_pool3d, k=3, stride=2, pad=1, count_include_pad=False.
// One launch handles both I and J (idx >= total -> J).
// ---------------------------------------------------------------------------
__global__ void pool_kernel2(const float* __restrict__ inA, const float* __restrict__ inB,
                             float* __restrict__ outA, float* __restrict__ outB,
                             int D, int H, int W, int oD, int oH, int oW, int total)
{
    int idx0 = blockIdx.x * 256 + threadIdx.x;
    if (idx0 >= 2 * total) return;
    const bool isB = idx0 >= total;
    int idx = isB ? idx0 - total : idx0;
    const float* in = isB ? inB : inA;
    float* out = isB ? outB : outA;

    int ow = idx % oW; int tmp = idx / oW;
    int oh = tmp % oH; tmp /= oH;
    int od = tmp % oD; int b = tmp / oD;

    int d0 = 2 * od - 1, h0 = 2 * oh - 1, w0 = 2 * ow - 1;
    int dlo = max(d0, 0), dhi = min(d0 + 3, D);
    int hlo = max(h0, 0), hhi = min(h0 + 3, H);
    int wlo = max(w0, 0), whi = min(w0 + 3, W);

    const float* ib = in + (size_t)b * D * H * W;
    float s = 0.f;
    for (int d = dlo; d < dhi; ++d)
        for (int h = hlo; h < hhi; ++h)
            for (int w = wlo; w < whi; ++w)
                s += ib[((size_t)d * H + h) * W + w];
    int cnt = (dhi - dlo) * (hhi - hlo) * (whi - wlo);
    out[idx] = s / (float)cnt;
}

__global__ void finalize_kernel(const double* __restrict__ acc, float* __restrict__ out)
{
    double m = acc[0] / 9830400.0 + acc[1] / 1228800.0 + acc[2] / 153600.0;
    out[0] = (float)(-m / 3.0);
}

extern "C" void kernel_launch(void* const* d_in, const int* in_sizes, int n_in,
                              void* d_out, int out_size, void* d_ws, size_t ws_size,
                              hipStream_t stream)
{
    const float* I0 = (const float*)d_in[0];
    const float* J0 = (const float*)d_in[1];
    float* out = (float*)d_out;

    char* ws = (char*)d_ws;
    double* acc = (double*)ws;                         // 3 doubles
    float* I1 = (float*)(ws + 256);
    float* J1 = I1 + (size_t)2 * 80 * 96 * 80;
    float* I2 = J1 + (size_t)2 * 80 * 96 * 80;
    float* J2 = I2 + (size_t)2 * 40 * 48 * 40;

    hipMemsetAsync(acc, 0, 3 * sizeof(double), stream);

    // ---- scale 0: 160x192x160, win=9 ----
    {
        int H = 192, W = 160, D = 160;
        int tilesH = 12, tilesW = 10;
        int chunksD = 8, chunkLen = 20;                 // 1920 blocks = 7.5/CU
        int blocks = 2 * tilesH * tilesW * chunksD;
        ncc_scale_kernel<9><<<blocks, 256, 0, stream>>>(I0, J0, D, H, W,
                                                        tilesH, tilesW, chunksD, chunkLen,
                                                        acc + 0);
    }
    // ---- pool level 0 -> 1 (I and J in one launch) ----
    {
        int total = 2 * 80 * 96 * 80;
        int blocks = (2 * total + 255) / 256;
        pool_kernel2<<<blocks, 256, 0, stream>>>(I0, J0, I1, J1,
                                                 160, 192, 160, 80, 96, 80, total);
    }
    // ---- scale 1: 80x96x80, win=7 ----
    {
        int H = 96, W = 80, D = 80;
        int tilesH = 6, tilesW = 5;
        int chunksD = 8, chunkLen = 10;                 // 480 blocks
        int blocks = 2 * tilesH * tilesW * chunksD;
        ncc_scale_kernel<7><<<blocks, 256, 0, stream>>>(I1, J1, D, H, W,
                                                        tilesH, tilesW, chunksD, chunkLen,
                                                        acc + 1);
    }
    // ---- pool level 1 -> 2 ----
    {
        int total = 2 * 40 * 48 * 40;
        int blocks = (2 * total + 255) / 256;
        pool_kernel2<<<blocks, 256, 0, stream>>>(I1, J1, I2, J2,
                                                 80, 96, 80, 40, 48, 40, total);
    }
    // ---- scale 2: 40x48x40, win=5 ----
    {
        int H = 48, W = 40, D = 40;
        int tilesH = 3, tilesW = 3;
        int chunksD = 5, chunkLen = 8;                  // 90 blocks (tiny scale)
        int blocks = 2 * tilesH * tilesW * chunksD;
        ncc_scale_kernel<5><<<blocks, 256, 0, stream>>>(I2, J2, D, H, W,
                                                        tilesH, tilesW, chunksD, chunkLen,
                                                        acc + 2);
    }

    finalize_kernel<<<1, 1, 0, stream>>>(acc, out);
}